// Round 2
// baseline (3477.013 us; speedup 1.0000x reference)
//
#include <hip/hip_runtime.h>
#include <hip/hip_bf16.h>
#include <cstdint>

#define SENT_LEN   256
#define SENT_BATCH 64
#define WORD_LEN   16
#define EMB        128
#define HID        256
#define CEMB       64
#define CHID       128
#define TAGS       50
#define K_IN       (EMB + CHID)   // 256

typedef __attribute__((ext_vector_type(8))) short short8;
typedef __attribute__((ext_vector_type(4))) float f32x4;

__device__ __forceinline__ float sigf(float x) {
    return 1.f / (1.f + __expf(-x));
}
__device__ __forceinline__ float tanhf_fast(float x) {
    x = fminf(fmaxf(x, -15.f), 15.f);
    float e = __expf(2.f * x);
    return (e - 1.f) / (e + 1.f);
}
__device__ __forceinline__ float bfu2f(unsigned short u) { return __uint_as_float(((unsigned)u) << 16); }
__device__ __forceinline__ unsigned short f2bfu(float f) {
    __hip_bfloat16 h = __float2bfloat16(f);
    return *reinterpret_cast<unsigned short*>(&h);
}

// ---------------- K1a: pre_c[ch][g] = b_c[g] + sum_k Wih_c[g][k]*char_emb[ch][k]
__global__ void prep_char(const float* __restrict__ Wih_c, const float* __restrict__ char_emb,
                          const float* __restrict__ bih_c, const float* __restrict__ bhh_c,
                          float* __restrict__ pre_c) {
    int ch = blockIdx.x;      // 128
    int g  = threadIdx.x;     // 512
    float acc = bih_c[g] + bhh_c[g];
    const float* w = Wih_c + g * CEMB;
    const float* e = char_emb + ch * CEMB;
#pragma unroll
    for (int k = 0; k < CEMB; k++) acc += w[k] * e[k];
    pre_c[ch * 512 + g] = acc;
}

// ---------------- K1b: zero the exchange flags (ws is re-poisoned before every launch)
__global__ void init_flags(int* __restrict__ flags) {
    flags[threadIdx.x] = 0;
}

// ---------------- K2: char LSTM. 256 blocks (chain t), 512 threads (gate g).
// Whh_c row register-resident; h/c/gates in LDS; 4 independent accumulators
// (break the 128-deep FMA dependency chain); prefetch next step's cid + pre row.
__global__ __launch_bounds__(512, 2) void char_lstm(
        const int* __restrict__ words, const float* __restrict__ Whh_c,
        const float* __restrict__ pre_c, float* __restrict__ cf) {
    int t = blockIdx.x;
    int g = threadIdx.x;
    __shared__ __align__(16) float h_s[CHID];
    __shared__ float c_s[CHID];
    __shared__ float g_s[512];

    float4 w4[32];
    const float4* wp = reinterpret_cast<const float4*>(Whh_c + g * CHID);
#pragma unroll
    for (int k = 0; k < 32; k++) w4[k] = wp[k];

    if (g < CHID) { h_s[g] = 0.f; c_s[g] = 0.f; }
    __syncthreads();

    const float4* h4 = reinterpret_cast<const float4*>(h_s);

    int cid0 = words[t];                 // s = 0
    float pre = pre_c[cid0 * 512 + g];

    for (int s = 0; s < SENT_BATCH * WORD_LEN; s++) {
        // prefetch next step's pre-activation row (2 chained L2 loads, ~1 step of slack)
        float pre_n = 0.f;
        if (s < SENT_BATCH * WORD_LEN - 1) {
            int cn = words[(s + 1) * SENT_LEN + t];
            pre_n = pre_c[cn * 512 + g];
        }
        float a0 = 0.f, a1 = 0.f, a2 = 0.f, a3 = 0.f;
#pragma unroll
        for (int k = 0; k < 32; k++) {
            float4 w = w4[k];
            float4 hv = h4[k];
            a0 = fmaf(w.x, hv.x, a0);
            a1 = fmaf(w.y, hv.y, a1);
            a2 = fmaf(w.z, hv.z, a2);
            a3 = fmaf(w.w, hv.w, a3);
        }
        g_s[g] = pre + ((a0 + a1) + (a2 + a3));
        __syncthreads();
        if (g < CHID) {
            float ig = sigf(g_s[g]);
            float fg = sigf(g_s[g + 128]);
            float gg = tanhf_fast(g_s[g + 256]);
            float og = sigf(g_s[g + 384]);
            float c = fg * c_s[g] + ig * gg;
            c_s[g] = c;
            float h = og * tanhf_fast(c);
            h_s[g] = h;
            if ((s & 15) == 15)
                cf[t * (SENT_BATCH * CHID) + (s >> 4) * CHID + g] = h;
        }
        __syncthreads();
        pre = pre_n;
    }
}

// ---------------- K3: xw[tb][g] = bf16( b_w[g] + sum_k x[tb][k]*Wih_w[g][k] )
#define BM 64
#define BN 128
#define BK 32
__global__ __launch_bounds__(256) void xw_gemm(
        const int* __restrict__ sentences, const float* __restrict__ word_emb,
        const float* __restrict__ cf, const float* __restrict__ Wih_w,
        const float* __restrict__ bih_w, const float* __restrict__ bhh_w,
        __hip_bfloat16* __restrict__ xw) {
    __shared__ float A_s[BM][BK + 1];
    __shared__ float B_s[BK][BN + 4];
    __shared__ int sid_s[BM];
    int tid = threadIdx.x;
    int row0 = blockIdx.y * BM;
    int col0 = blockIdx.x * BN;
    if (tid < BM) sid_s[tid] = sentences[row0 + tid];
    __syncthreads();

    float acc[8][4] = {};
    int tx = tid & 31, tyy = tid >> 5;

    for (int k0 = 0; k0 < K_IN; k0 += BK) {
#pragma unroll
        for (int i = 0; i < 2; i++) {
            int idx = tid + i * 256;
            int r = idx >> 3, k4 = idx & 7;
            int k = k0 + k4 * 4;
            float4 v;
            if (k < EMB)
                v = reinterpret_cast<const float4*>(word_emb + (size_t)sid_s[r] * EMB + k)[0];
            else
                v = reinterpret_cast<const float4*>(cf + (size_t)(row0 + r) * CHID + (k - EMB))[0];
            A_s[r][k4 * 4 + 0] = v.x; A_s[r][k4 * 4 + 1] = v.y;
            A_s[r][k4 * 4 + 2] = v.z; A_s[r][k4 * 4 + 3] = v.w;
        }
#pragma unroll
        for (int i = 0; i < 4; i++) {
            int idx = tid + i * 256;
            int gg = idx >> 3, k4 = idx & 7;
            float4 v = reinterpret_cast<const float4*>(Wih_w + (size_t)(col0 + gg) * K_IN + k0 + k4 * 4)[0];
            B_s[k4 * 4 + 0][gg] = v.x; B_s[k4 * 4 + 1][gg] = v.y;
            B_s[k4 * 4 + 2][gg] = v.z; B_s[k4 * 4 + 3][gg] = v.w;
        }
        __syncthreads();
#pragma unroll
        for (int kk = 0; kk < BK; kk++) {
            float4 bv = reinterpret_cast<const float4*>(&B_s[kk][tx * 4])[0];
#pragma unroll
            for (int i = 0; i < 8; i++) {
                float av = A_s[tyy * 8 + i][kk];
                acc[i][0] += av * bv.x; acc[i][1] += av * bv.y;
                acc[i][2] += av * bv.z; acc[i][3] += av * bv.w;
            }
        }
        __syncthreads();
    }
#pragma unroll
    for (int i = 0; i < 8; i++) {
        int r = row0 + tyy * 8 + i;
#pragma unroll
        for (int j = 0; j < 4; j++) {
            int cg = col0 + tx * 4 + j;
            xw[(size_t)r * 1024 + cg] = __float2bfloat16(acc[i][j] + bih_w[cg] + bhh_w[cg]);
        }
    }
}

// ---------------- K4: word LSTM, chain-batched MFMA, gate-split across 16 blocks.
// Block bj owns hidden slice j in [bj*16, bj*16+16) => 64 gate rows (4 gate types x 16 j).
// GEMM per step: A = h[64 chains][256] (bf16, from exchange buffer in L2),
//                B = Whh rows (register-resident bf16 frags, 128 VGPRs/lane),
//                C init = xw pre-activations. 256 threads = 4 waves, wave w = M-tile w.
// Cross-block exchange: h_ex (bf16, double-buffered) + per-block monotonic seq flags.
__global__ __launch_bounds__(256, 1) void word_lstm(
        const __hip_bfloat16* __restrict__ xw_, const float* __restrict__ Whh_w,
        unsigned short* __restrict__ h_ex, int* __restrict__ flags,
        float* __restrict__ h_out) {
    const unsigned short* xw = reinterpret_cast<const unsigned short*>(xw_);
    int bj   = blockIdx.x;          // 0..15
    int tid  = threadIdx.x;         // 0..255
    int lane = tid & 63;
    int w    = tid >> 6;            // wave id = M-tile
    int m0   = w * 16;
    int l15  = lane & 15;
    int lq   = lane >> 4;

    __shared__ float g_s[4 * 64 * 16];   // [gate_type][chain][j_local], 16 KB

    // ---- B fragments: Whh_w rows for this block's 64 gates, bf16, register-resident.
    // b-frag (n-tile n, k-tile kt): lane holds B^T[row = gate][k = kt*32 + lq*8 + j], j=0..7
    short8 bfr[4][8];
#pragma unroll
    for (int n = 0; n < 4; n++) {
        int grow = n * 256 + bj * 16 + l15;
        const float* wr = Whh_w + (size_t)grow * HID;
#pragma unroll
        for (int kt = 0; kt < 8; kt++) {
            float4 v0 = reinterpret_cast<const float4*>(wr + kt * 32 + lq * 8)[0];
            float4 v1 = reinterpret_cast<const float4*>(wr + kt * 32 + lq * 8 + 4)[0];
            short8 b;
            b[0] = (short)f2bfu(v0.x); b[1] = (short)f2bfu(v0.y);
            b[2] = (short)f2bfu(v0.z); b[3] = (short)f2bfu(v0.w);
            b[4] = (short)f2bfu(v1.x); b[5] = (short)f2bfu(v1.y);
            b[6] = (short)f2bfu(v1.z); b[7] = (short)f2bfu(v1.w);
            bfr[n][kt] = b;
        }
    }

    // per-thread c state: uu=0..3 -> chain b = (tid>>4) + 16*uu, j_local = tid&15
    float cst[4] = {0.f, 0.f, 0.f, 0.f};
    int ub = tid >> 4;
    int uj = tid & 15;

    for (int t = 0; t < SENT_LEN; t++) {
        // ---- C init from xw pre-activations (independent of h; issues before poll)
        f32x4 acc[4];
#pragma unroll
        for (int n = 0; n < 4; n++) {
            int g = n * 256 + bj * 16 + l15;
#pragma unroll
            for (int r = 0; r < 4; r++) {
                int b = m0 + lq * 4 + r;
                acc[n][r] = bfu2f(xw[((size_t)t * SENT_BATCH + b) * 1024 + g]);
            }
        }

        if (t > 0) {
            // ---- wait for all blocks to have published h_{t-1}
            while (__hip_atomic_load(&flags[(lane & 15) * 16], __ATOMIC_ACQUIRE,
                                     __HIP_MEMORY_SCOPE_AGENT) < t) { }
            __threadfence();
            // ---- A fragments direct from L2: h_{t-1} in h_ex[(t-1)&1]
            const unsigned short* hp = h_ex + ((size_t)((t - 1) & 1)) * (64 * 256)
                                       + (size_t)(m0 + l15) * 256 + lq * 8;
            uint4 av[8];
#pragma unroll
            for (int kt = 0; kt < 8; kt++)
                av[kt] = reinterpret_cast<const uint4*>(hp + kt * 32)[0];
#pragma unroll
            for (int kt = 0; kt < 8; kt++) {
                short8 a = *reinterpret_cast<short8*>(&av[kt]);
#pragma unroll
                for (int n = 0; n < 4; n++)
                    acc[n] = __builtin_amdgcn_mfma_f32_16x16x32_bf16(a, bfr[n][kt], acc[n], 0, 0, 0);
            }
        }

        // ---- scatter gates to LDS: g_s[n][b][j]
#pragma unroll
        for (int n = 0; n < 4; n++) {
#pragma unroll
            for (int r = 0; r < 4; r++) {
                int b = m0 + lq * 4 + r;
                g_s[n * 1024 + b * 16 + l15] = acc[n][r];
            }
        }
        __syncthreads();

        // ---- nonlinearity: 4 (chain,j) updates per thread, conflict-free LDS reads
#pragma unroll
        for (int uu = 0; uu < 4; uu++) {
            int b = ub + 16 * uu;
            int base = b * 16 + uj;
            float gi = g_s[base];
            float gf = g_s[1024 + base];
            float gg = g_s[2048 + base];
            float go = g_s[3072 + base];
            float c = sigf(gf) * cst[uu] + sigf(gi) * tanhf_fast(gg);
            cst[uu] = c;
            float h = sigf(go) * tanhf_fast(c);
            int jg = bj * 16 + uj;
            h_out[((size_t)t * SENT_BATCH + b) * HID + jg] = h;
            h_ex[((size_t)(t & 1)) * (64 * 256) + (size_t)b * 256 + jg] = f2bfu(h);
        }
        __syncthreads();   // drains the h_ex stores (vmcnt(0) before s_barrier)
        if (tid == 0) {
            __threadfence();
            __hip_atomic_store(&flags[bj * 16], t + 1, __ATOMIC_RELEASE,
                               __HIP_MEMORY_SCOPE_AGENT);
        }
    }
}

// ---------------- K5: tag projection + log_softmax.
__global__ __launch_bounds__(256) void tag_logsoftmax(
        const float* __restrict__ h_out, const float* __restrict__ W_tag,
        const float* __restrict__ b_tag, float* __restrict__ out) {
    __shared__ float wt_s[TAGS * 257];
    __shared__ float hr_s[4 * HID];
    int tid = threadIdx.x;
    int row0 = blockIdx.x * 4;
#pragma unroll 2
    for (int i = 0; i < TAGS; i++) wt_s[i * 257 + tid] = W_tag[i * HID + tid];
#pragma unroll
    for (int w = 0; w < 4; w++) hr_s[w * HID + tid] = h_out[(size_t)(row0 + w) * HID + tid];
    __syncthreads();

    int w = tid >> 6, l = tid & 63;
    float acc = 0.f;
    if (l < TAGS) {
        acc = b_tag[l];
        const float* hr = hr_s + w * HID;
        const float* wr = wt_s + l * 257;
#pragma unroll 4
        for (int k = 0; k < HID; k++) acc += hr[k] * wr[k];
    }
    float m = (l < TAGS) ? acc : -1e30f;
#pragma unroll
    for (int off = 32; off; off >>= 1) m = fmaxf(m, __shfl_xor(m, off, 64));
    float e = (l < TAGS) ? __expf(acc - m) : 0.f;
    float ssum = e;
#pragma unroll
    for (int off = 32; off; off >>= 1) ssum += __shfl_xor(ssum, off, 64);
    float lse = m + __logf(ssum);
    if (l < TAGS) out[(size_t)(row0 + w) * TAGS + l] = acc - lse;
}

extern "C" void kernel_launch(void* const* d_in, const int* in_sizes, int n_in,
                              void* d_out, int out_size, void* d_ws, size_t ws_size,
                              hipStream_t stream) {
    (void)in_sizes; (void)n_in; (void)out_size; (void)ws_size;
    const int*   sentences = (const int*)d_in[0];
    const int*   words     = (const int*)d_in[1];
    const float* word_emb  = (const float*)d_in[4];
    const float* char_emb  = (const float*)d_in[5];
    const float* Wih_c     = (const float*)d_in[6];
    const float* Whh_c     = (const float*)d_in[7];
    const float* bih_c     = (const float*)d_in[8];
    const float* bhh_c     = (const float*)d_in[9];
    const float* Wih_w     = (const float*)d_in[10];
    const float* Whh_w     = (const float*)d_in[11];
    const float* bih_w     = (const float*)d_in[12];
    const float* bhh_w     = (const float*)d_in[13];
    const float* W_tag     = (const float*)d_in[14];
    const float* b_tag     = (const float*)d_in[15];
    float* out = (float*)d_out;

    char* ws = (char*)d_ws;
    size_t off = 0;
    float* pre_c = (float*)(ws + off);              off += 512 * 128 * sizeof(float);
    float* cf = (float*)(ws + off);                 off += (size_t)SENT_LEN * SENT_BATCH * CHID * sizeof(float);
    __hip_bfloat16* xw = (__hip_bfloat16*)(ws + off); off += (size_t)SENT_LEN * SENT_BATCH * 1024 * sizeof(__hip_bfloat16);
    float* h_out = (float*)(ws + off);              off += (size_t)SENT_LEN * SENT_BATCH * HID * sizeof(float);
    unsigned short* h_ex = (unsigned short*)(ws + off); off += 2 * 64 * 256 * sizeof(unsigned short);
    int* flags = (int*)(ws + off);                  off += 256 * sizeof(int);

    hipLaunchKernelGGL(prep_char, dim3(128), dim3(512), 0, stream,
                       Wih_c, char_emb, bih_c, bhh_c, pre_c);
    hipLaunchKernelGGL(init_flags, dim3(1), dim3(256), 0, stream, flags);
    hipLaunchKernelGGL(char_lstm, dim3(256), dim3(512), 0, stream,
                       words, Whh_c, pre_c, cf);
    hipLaunchKernelGGL(xw_gemm, dim3(1024 / BN, (SENT_LEN * SENT_BATCH) / BM), dim3(256), 0, stream,
                       sentences, word_emb, cf, Wih_w, bih_w, bhh_w, xw);
    hipLaunchKernelGGL(word_lstm, dim3(16), dim3(256), 0, stream,
                       xw, Whh_w, h_ex, flags, h_out);
    hipLaunchKernelGGL(tag_logsoftmax, dim3((SENT_LEN * SENT_BATCH) / 4), dim3(256), 0, stream,
                       h_out, W_tag, b_tag, out);
}